// Round 10
// baseline (1019.139 us; speedup 1.0000x reference)
//
#include <hip/hip_runtime.h>
#include <math.h>

#define S_TOT 2112
#define SPAD  2176   // 17 * 128
#define DMODEL 768
#define QKVLD 2304
#define NMEM 64
#define NHEAD 12
#define HDIM 64
#define NQT 33       // number of 64-row q tiles
#define CHUNK 9      // k-tiles per attention chunk
#define NZ 4         // max chunks = ceil(33/9)

typedef unsigned short ushort_t;
typedef __attribute__((ext_vector_type(8))) short short8;
typedef __attribute__((ext_vector_type(4))) float f32x4;

__device__ __forceinline__ ushort_t f2bf(float f) {
    unsigned int u = __builtin_bit_cast(unsigned int, f);
    u = (u + 0x7FFFu + ((u >> 16) & 1u)) >> 16;   // RNE
    return (ushort_t)u;
}
__device__ __forceinline__ float bf2f(ushort_t u) {
    unsigned int x = ((unsigned int)u) << 16;
    return __builtin_bit_cast(float, x);
}

// async global->LDS, 16B per lane (dwordx4). LDS dest is wave-uniform base +
// lane*16 (HW rule, m104); global src is per-lane (pre-swizzle goes here).
__device__ __forceinline__ void gl_lds16(const ushort_t* g, ushort_t* s) {
    __builtin_amdgcn_global_load_lds(
        (const __attribute__((address_space(1))) unsigned int*)g,
        (__attribute__((address_space(3))) unsigned int*)s,
        16, 0, 0);
}

// wait lgkmcnt(0) only — leave vmcnt/expcnt open so prefetch loads stay in flight
#define WAIT_LGKM() __builtin_amdgcn_s_waitcnt(0xC07F)
#define BAR()       __builtin_amdgcn_s_barrier()

// ---------------- f32 -> bf16 weight convert, ALL 4 LAYERS in one launch.
// Per-layer dst layout: [wqkv 3DD | wob DD | w1b DF | w2b DF], stride PERL.
__global__ __launch_bounds__(256) void cvt_all_kernel(
    const float* __restrict__ wq, const float* __restrict__ wk,
    const float* __restrict__ wv, const float* __restrict__ wo,
    const float* __restrict__ w1, const float* __restrict__ w2,
    ushort_t* __restrict__ wAll)
{
    const int DD = DMODEL * DMODEL;               // 589824
    const int DF = DMODEL * 4 * DMODEL;           // 2359296
    const int DDv = DD / 4;                       // 147456
    const int DFv = DF / 4;                       // 589824
    const int PERLv = 4 * DDv + 2 * DFv;          // 1769472 vec4 per layer
    int i = blockIdx.x * 256 + threadIdx.x;
    int layer = i / PERLv;
    int r = i - layer * PERLv;
    const float* src;
    if (r < 3 * DDv) {
        if (r < DDv)          src = wq + (size_t)layer * DD + (size_t)r * 4;
        else if (r < 2 * DDv) src = wk + (size_t)layer * DD + (size_t)(r - DDv) * 4;
        else                  src = wv + (size_t)layer * DD + (size_t)(r - 2 * DDv) * 4;
    } else if (r < 4 * DDv) {
        src = wo + (size_t)layer * DD + (size_t)(r - 3 * DDv) * 4;
    } else if (r < 4 * DDv + DFv) {
        src = w1 + (size_t)layer * DF + (size_t)(r - 4 * DDv) * 4;
    } else {
        src = w2 + (size_t)layer * DF + (size_t)(r - 4 * DDv - DFv) * 4;
    }
    ushort_t* dst = wAll + (size_t)layer * PERLv * 4 + (size_t)r * 4;
    float4 v = *(const float4*)src;
    ushort4 o;
    o.x = f2bf(v.x); o.y = f2bf(v.y); o.z = f2bf(v.z); o.w = f2bf(v.w);
    *(ushort4*)dst = o;
}

// ---------------- embedding (pads rows >= S_TOT with zeros)
__global__ __launch_bounds__(256) void embed_kernel(
    const int* __restrict__ tokens, const float* __restrict__ emb,
    const float* __restrict__ pos, const float* __restrict__ mem,
    float* __restrict__ x)
{
    int s = blockIdx.x;
    int tid = threadIdx.x;
    float* xr = x + (size_t)s * DMODEL;
    if (s >= S_TOT) {
        for (int d = tid; d < DMODEL; d += 256) xr[d] = 0.0f;
    } else if (s < NMEM) {
        const float* mr = mem + (size_t)s * DMODEL;
        for (int d = tid; d < DMODEL; d += 256) xr[d] = mr[d];
    } else {
        int t = s - NMEM;
        int tok = tokens[t];
        const float* er = emb + (size_t)tok * DMODEL;
        const float* pr = pos + (size_t)t * DMODEL;
        for (int d = tid; d < DMODEL; d += 256) xr[d] = er[d] + pr[d];
    }
}

// ---------------- layernorm: wave-shuffle reduce, 2 barriers total
template <typename OUT>
__global__ __launch_bounds__(256) void ln_kernel(
    const float* __restrict__ X, const float* __restrict__ g,
    const float* __restrict__ b, OUT* __restrict__ Y)
{
    __shared__ float red[8];
    int row = blockIdx.x, tid = threadIdx.x;
    int wv = tid >> 6, ln = tid & 63;
    const float* xr = X + (size_t)row * DMODEL;
    float v0 = xr[tid], v1 = xr[tid + 256], v2 = xr[tid + 512];

    // pass 1: mean
    float s = v0 + v1 + v2;
#pragma unroll
    for (int off = 1; off < 64; off <<= 1) s += __shfl_xor(s, off);
    if (ln == 0) red[wv] = s;
    __syncthreads();
    float mu = (red[0] + red[1] + red[2] + red[3]) * (1.0f / 768.0f);

    // pass 2: variance of deviations
    float d0 = v0 - mu, d1 = v1 - mu, d2 = v2 - mu;
    float q = d0 * d0 + d1 * d1 + d2 * d2;
#pragma unroll
    for (int off = 1; off < 64; off <<= 1) q += __shfl_xor(q, off);
    if (ln == 0) red[4 + wv] = q;
    __syncthreads();
    float var = (red[4] + red[5] + red[6] + red[7]) * (1.0f / 768.0f);
    float inv = rsqrtf(var + 1e-5f);

    OUT* yr = Y + (size_t)row * DMODEL;
    float o0 = d0 * inv * g[tid]       + b[tid];
    float o1 = d1 * inv * g[tid + 256] + b[tid + 256];
    float o2 = d2 * inv * g[tid + 512] + b[tid + 512];
    if constexpr (sizeof(OUT) == 2) {
        yr[tid] = f2bf(o0); yr[tid + 256] = f2bf(o1); yr[tid + 512] = f2bf(o2);
    } else {
        yr[tid] = o0; yr[tid + 256] = o1; yr[tid + 512] = o2;
    }
}

// ---------------- bf16 MFMA GEMM, m97 structure: 4 waves (256 thr), 128x128
// tile, BK=32, global_load_lds width=16 staging (no reg round-trip, no
// per-thread ds_writes), 2 LDS buffers, ONE __syncthreads per K-step (its
// vmcnt0+lgkm0 drain commits the async loads). Each wave owns a 64x64 sub-tile
// (acc[4][4]): 8 ds_read_b128 per 16 MFMAs (0.5 reads/MFMA, half the previous
// pressure). Swizzle per rule #21: LDS dest LINEAR (gl_lds requirement),
// global SOURCE pre-swizzled chunk = (l&3)^((row>>1)&3), fragment reads use
// the matching XOR. 32 KB LDS + __launch_bounds__(256,4) -> 4 blocks/CU:
// independent blocks cover each other's barrier drains.
// C = act(A.B^T + bias) (+resid). A:[M,K] B:[N,K] bf16 row-major.
// XCD-bijective block swizzle. Split-K via gridDim.z (atomicAdd f32 partials).
__global__ __launch_bounds__(256, 4) void gemm_mfma(
    const ushort_t* __restrict__ A, const ushort_t* __restrict__ B,
    const float* __restrict__ bias, const float* __restrict__ resid,
    void* __restrict__ Cp, int K, int ldc, int ncol0, int act, int c_bf16)
{
    __shared__ ushort_t As[2][4096];   // 128 rows x 32 cols, 64 B/row
    __shared__ ushort_t Bs[2][4096];
    int tid = threadIdx.x;
    int l = tid & 63, w = tid >> 6;    // 4 waves
    int wr = w >> 1, wc = w & 1;       // each wave: 64x64 sub-tile

    // bijective XCD swizzle (m204) on the flattened (x,y) index; z untouched.
    int gx = gridDim.x;
    int nwg = gx * gridDim.y;
    int orig = blockIdx.x + gx * blockIdx.y;
    int q = nwg >> 3, r = nwg & 7;
    int xcd = orig & 7, loc = orig >> 3;
    int swz = (xcd < r ? xcd * (q + 1) : r * (q + 1) + (xcd - r) * q) + loc;
    int m0 = (swz / gx) * 128, n0 = (swz % gx) * 128;

    int kz = blockIdx.z;
    int nsplit = gridDim.z;
    int Kc = K / nsplit;              // multiple of 32 for all uses
    bool split = (nsplit > 1);

    // staging geometry: per wave, two 16-row sections each of A and B.
    // gl_lds writes LDS linearly: lane lnew covers row = sec + l>>2, physical
    // 16B-chunk p = l&3. Pre-swizzled source: logical chunk c = p^((row>>1)&3).
    int lrow = l >> 2;
    int r0 = w * 32, r1 = w * 32 + 16;
    int grow0 = r0 + lrow, grow1 = r1 + lrow;
    int gc0 = (l & 3) ^ ((grow0 >> 1) & 3);
    int gc1 = (l & 3) ^ ((grow1 >> 1) & 3);
    const ushort_t* ApS0 = A + (size_t)(m0 + grow0) * K + kz * Kc + gc0 * 8;
    const ushort_t* ApS1 = A + (size_t)(m0 + grow1) * K + kz * Kc + gc1 * 8;
    const ushort_t* BpS0 = B + (size_t)(n0 + grow0) * K + kz * Kc + gc0 * 8;
    const ushort_t* BpS1 = B + (size_t)(n0 + grow1) * K + kz * Kc + gc1 * 8;
    int lb0 = r0 * 32, lb1 = r1 * 32;  // wave-uniform LDS bases (ushort idx)

    // fragment LDS byte offsets (verified layout + matching XOR)
    int kc = l >> 4, mr = l & 15;
    int aoff[4], boff[4];
#pragma unroll
    for (int i = 0; i < 4; ++i) {
        int rr = wr * 64 + i * 16 + mr;
        aoff[i] = rr * 64 + ((kc ^ ((rr >> 1) & 3)) << 4);
        rr = wc * 64 + i * 16 + mr;
        boff[i] = rr * 64 + ((kc ^ ((rr >> 1) & 3)) << 4);
    }

    f32x4 acc[4][4];
#pragma unroll
    for (int i = 0; i < 4; ++i)
#pragma unroll
        for (int j = 0; j < 4; ++j)
            acc[i][j] = (f32x4){0.f, 0.f, 0.f, 0.f};

    int nk = Kc >> 5;                 // BK = 32

    auto stage = [&](int bi, int kt) {
        int ko = kt << 5;
        gl_lds16(ApS0 + ko, &As[bi][lb0]);
        gl_lds16(ApS1 + ko, &As[bi][lb1]);
        gl_lds16(BpS0 + ko, &Bs[bi][lb0]);
        gl_lds16(BpS1 + ko, &Bs[bi][lb1]);
    };

    stage(0, 0);
    __syncthreads();                  // vmcnt(0) drain -> tile0 in LDS

    for (int k = 0; k < nk; ++k) {
        if (k + 1 < nk) stage((k + 1) & 1, k + 1);   // async, in flight
        const char* bA = (const char*)As[k & 1];
        const char* bB = (const char*)Bs[k & 1];
        short8 af[4], bfr[4];
#pragma unroll
        for (int i = 0; i < 4; ++i) {
            af[i]  = *(const short8*)(bA + aoff[i]);
            bfr[i] = *(const short8*)(bB + boff[i]);
        }
#pragma unroll
        for (int i = 0; i < 4; ++i)
#pragma unroll
            for (int j = 0; j < 4; ++j)
                acc[i][j] = __builtin_amdgcn_mfma_f32_16x16x32_bf16(af[i], bfr[j], acc[i][j], 0, 0, 0);
        __syncthreads();              // drains vmcnt(0): tile k+1 committed
    }

    // epilogue: D row = (l>>4)*4 + reg, col = l&15 (m89-verified)
    int lq = l >> 4;
#pragma unroll
    for (int i = 0; i < 4; ++i) {
#pragma unroll
        for (int rr = 0; rr < 4; ++rr) {
            int m = m0 + wr * 64 + i * 16 + lq * 4 + rr;
#pragma unroll
            for (int j = 0; j < 4; ++j) {
                int n = n0 + wc * 64 + j * 16 + mr;
                float v = acc[i][j][rr];
                if (bias && (!split || kz == 0)) v += bias[n];
                if (act) {
                    // tanh-GELU via sigmoid: 0.5u(1+tanh t) = u/(1+e^{-2t})
                    float u = v;
                    float t = 0.7978845608028654f * (u + 0.044715f * u * u * u);
                    v = u / (1.0f + __expf(-2.0f * t));
                }
                size_t idx = (size_t)m * ldc + ncol0 + n;
                if (split) {
                    atomicAdd((float*)Cp + idx, v);
                } else {
                    if (resid) v += resid[idx];
                    if (c_bf16) ((ushort_t*)Cp)[idx] = f2bf(v);
                    else        ((float*)Cp)[idx] = v;
                }
            }
        }
    }
}

// ---------------- MFMA flash attention, chunked (flash-decode style).
// Block = (q-tile, head, k-chunk of CHUNK tiles), 4 waves. Each chunk runs the
// double-buffered flash inner loop over its k-range and writes an UNNORMALIZED
// partial numerator (bf16) + per-row (m,l) to scratch; attn_combine merges.
__global__ __launch_bounds__(256) void attn_mfma(
    const ushort_t* __restrict__ qkv, ushort_t* __restrict__ Opart,
    float* __restrict__ ml)
{
    __shared__ ushort_t Qs[64][72];
    __shared__ ushort_t Ks[2][64][72];
    __shared__ ushort_t Vt[2][64][72];
    __shared__ ushort_t Ps[64][72];

    int qt = blockIdx.x;
    int h  = blockIdx.y;
    int z  = blockIdx.z;
    int kt0 = z * CHUNK;
    if (kt0 > qt) return;                       // inactive chunk (uniform exit)
    int kt1 = min(kt0 + CHUNK, qt + 1);

    int tid = threadIdx.x;
    int w = tid >> 6, lane = tid & 63;
    int quad = lane >> 4, l16 = lane & 15;
    int sr = lane;
    int dg = w;

    const size_t TSTRIDE = (size_t)64 * QKVLD;

    // stage Q tile
    {
        const ushort_t* qp = qkv + (size_t)(qt * 64 + sr) * QKVLD + h * HDIM + dg * 16;
        *(short8*)&Qs[sr][dg * 16]     = *(const short8*)qp;
        *(short8*)&Qs[sr][dg * 16 + 8] = *(const short8*)(qp + 8);
    }

    // prologue: tile kt0 -> regs -> buf0; tile kt0+1 -> regs (in flight).
    const ushort_t* kp = qkv + (size_t)(kt0 * 64 + sr) * QKVLD + DMODEL + h * HDIM + dg * 16;
    const ushort_t* vp = kp + DMODEL;
    short8 pk0 = *(const short8*)kp, pk1 = *(const short8*)(kp + 8);
    short8 pv0 = *(const short8*)vp, pv1 = *(const short8*)(vp + 8);
    kp += TSTRIDE; vp += TSTRIDE;

    *(short8*)&Ks[0][sr][dg * 16]     = pk0;
    *(short8*)&Ks[0][sr][dg * 16 + 8] = pk1;
#pragma unroll
    for (int j = 0; j < 8; ++j) Vt[0][dg * 16 + j][sr] = (ushort_t)pv0[j];
#pragma unroll
    for (int j = 0; j < 8; ++j) Vt[0][dg * 16 + 8 + j][sr] = (ushort_t)pv1[j];

    pk0 = *(const short8*)kp; pk1 = *(const short8*)(kp + 8);
    pv0 = *(const short8*)vp; pv1 = *(const short8*)(vp + 8);
    kp += TSTRIDE; vp += TSTRIDE;

    WAIT_LGKM(); BAR();

    short8 qf[2];
    qf[0] = *(const short8*)&Qs[w * 16 + l16][quad * 8];
    qf[1] = *(const short8*)&Qs[w * 16 + l16][32 + quad * 8];

    float mstate[4] = {-1e30f, -1e30f, -1e30f, -1e30f};
    float lstate[4] = {0.f, 0.f, 0.f, 0.f};
    f32x4 accO[4];
#pragma unroll
    for (int j = 0; j < 4; ++j) accO[j] = (f32x4){0.f, 0.f, 0.f, 0.f};

    for (int kt = kt0; kt < kt1; ++kt) {
        int cb = (kt - kt0) & 1;

        // QK^T on buffer cb
        f32x4 sacc[4];
#pragma unroll
        for (int nt = 0; nt < 4; ++nt) {
            sacc[nt] = (f32x4){0.f, 0.f, 0.f, 0.f};
            short8 kf0 = *(const short8*)&Ks[cb][nt * 16 + l16][quad * 8];
            short8 kf1 = *(const short8*)&Ks[cb][nt * 16 + l16][32 + quad * 8];
            sacc[nt] = __builtin_amdgcn_mfma_f32_16x16x32_bf16(qf[0], kf0, sacc[nt], 0, 0, 0);
            sacc[nt] = __builtin_amdgcn_mfma_f32_16x16x32_bf16(qf[1], kf1, sacc[nt], 0, 0, 0);
        }

        // commit prefetched tile kt+1 into the other buffer; issue loads kt+2.
        if (kt + 1 < kt1) {
            int nb = cb ^ 1;
            *(short8*)&Ks[nb][sr][dg * 16]     = pk0;
            *(short8*)&Ks[nb][sr][dg * 16 + 8] = pk1;
#pragma unroll
            for (int j = 0; j < 8; ++j) Vt[nb][dg * 16 + j][sr] = (ushort_t)pv0[j];
#pragma unroll
            for (int j = 0; j < 8; ++j) Vt[nb][dg * 16 + 8 + j][sr] = (ushort_t)pv1[j];
            pk0 = *(const short8*)kp; pk1 = *(const short8*)(kp + 8);
            pv0 = *(const short8*)vp; pv1 = *(const short8*)(vp + 8);
            kp += TSTRIDE; vp += TSTRIDE;
        }

        bool diag = (kt == qt);
        float s[4][4], rmax[4];
#pragma unroll
        for (int r = 0; r < 4; ++r) rmax[r] = -1e30f;
#pragma unroll
        for (int nt = 0; nt < 4; ++nt)
#pragma unroll
            for (int r = 0; r < 4; ++r) {
                float v = sacc[nt][r] * 0.125f;
                if (diag && (nt * 16 + l16) > (w * 16 + quad * 4 + r)) v = -1e30f;
                s[nt][r] = v;
                rmax[r] = fmaxf(rmax[r], v);
            }
#pragma unroll
        for (int r = 0; r < 4; ++r) {
            rmax[r] = fmaxf(rmax[r], __shfl_xor(rmax[r], 1));
            rmax[r] = fmaxf(rmax[r], __shfl_xor(rmax[r], 2));
            rmax[r] = fmaxf(rmax[r], __shfl_xor(rmax[r], 4));
            rmax[r] = fmaxf(rmax[r], __shfl_xor(rmax[r], 8));
        }
        float alpha[4];
#pragma unroll
        for (int r = 0; r < 4; ++r) {
            float mnew = fmaxf(mstate[r], rmax[r]);
            alpha[r] = __expf(mstate[r] - mnew);
            mstate[r] = mnew;
        }
        float rsum[4] = {0.f, 0.f, 0.f, 0.f};
#pragma unroll
        for (int nt = 0; nt < 4; ++nt)
#pragma unroll
            for (int r = 0; r < 4; ++r) {
                float p = __expf(s[nt][r] - mstate[r]);
                Ps[w * 16 + quad * 4 + r][nt * 16 + l16] = f2bf(p);
                rsum[r] += p;
            }
#pragma unroll
        for (int r = 0; r < 4; ++r) {
            rsum[r] += __shfl_xor(rsum[r], 1);
            rsum[r] += __shfl_xor(rsum[r], 2);
            rsum[r] += __shfl_xor(rsum[r], 4);
            rsum[r] += __shfl_xor(rsum[r], 8);
            lstate[r] = lstate[r] * alpha[r] + rsum[r];
        }
#pragma unroll
        for (int j = 0; j < 4; ++j)
#pragma unroll
            for (int r = 0; r < 4; ++r) accO[j][r] *= alpha[r];

        short8 pf0 = *(const short8*)&Ps[w * 16 + l16][quad * 8];
        short8 pf1 = *(const short8*)&Ps[w * 16 + l16][32 + quad * 8];
#pragma unroll
        for (int j = 0; j < 4; ++j) {
            short8 vf0 = *(const short8*)&Vt[cb][j * 16 + l16][quad * 8];
            short8 vf1 = *(const short8*)&Vt[cb][j * 16 + l16][32 + quad * 8];
            accO[j] = __builtin_amdgcn_mfma_f32_16x16x32_bf16(pf0, vf0, accO[j], 0, 0, 0);
            accO[j] = __builtin_amdgcn_mfma_f32_16x16x32_bf16(pf1, vf1, accO[j], 0, 0, 0);
        }

        WAIT_LGKM(); BAR();
    }

    // epilogue: write unnormalized partial numerator + (m,l) per row
    size_t pidx = (size_t)(h * NQT + qt) * NZ + z;
#pragma unroll
    for (int j = 0; j < 4; ++j)
#pragma unroll
        for (int r = 0; r < 4; ++r) {
            int row = w * 16 + quad * 4 + r;
            Opart[pidx * 4096 + row * 64 + j * 16 + l16] = f2bf(accO[j][r]);
        }
    if (l16 == 0) {
        float* mlr = ml + pidx * 128;
#pragma unroll
        for (int r = 0; r < 4; ++r) {
            int row = w * 16 + quad * 4 + r;
            mlr[row * 2]     = mstate[r];
            mlr[row * 2 + 1] = lstate[r];
        }
    }
}

// ---------------- merge attention chunks -> attb
__global__ __launch_bounds__(256) void attn_combine(
    const ushort_t* __restrict__ Opart, const float* __restrict__ ml,
    ushort_t* __restrict__ att)
{
    int qt = blockIdx.x, h = blockIdx.y;
    int nch = (qt + CHUNK) / CHUNK;   // ceil((qt+1)/CHUNK)
    int t = threadIdx.x;
    int row = t >> 2, c0 = (t & 3) << 4;
    size_t pb = (size_t)(h * NQT + qt) * NZ;

    float mv[NZ], lv[NZ];
    float M = -1e30f;
#pragma unroll
    for (int z = 0; z < NZ; ++z) {
        mv[z] = -1e30f; lv[z] = 0.f;
        if (z < nch) {
            const float* p = ml + (pb + z) * 128 + row * 2;
            mv[z] = p[0]; lv[z] = p[1];
            M = fmaxf(M, mv[z]);
        }
    }
    float denom = 0.f;
    float sc[NZ];
#pragma unroll
    for (int z = 0; z < NZ; ++z) {
        sc[z] = 0.f;
        if (z < nch) { sc[z] = __expf(mv[z] - M); denom += sc[z] * lv[z]; }
    }
    float inv = 1.0f / denom;

    float o[16];
#pragma unroll
    for (int i = 0; i < 16; ++i) o[i] = 0.f;
#pragma unroll
    for (int z = 0; z < NZ; ++z) {
        if (z < nch) {
            const ushort_t* op = Opart + (pb + z) * 4096 + row * 64 + c0;
            short8 a0 = *(const short8*)op;
            short8 a1 = *(const short8*)(op + 8);
#pragma unroll
            for (int i = 0; i < 8; ++i) o[i]     += sc[z] * bf2f((ushort_t)a0[i]);
#pragma unroll
            for (int i = 0; i < 8; ++i) o[i + 8] += sc[z] * bf2f((ushort_t)a1[i]);
        }
    }
    ushort_t* dst = att + (size_t)(qt * 64 + row) * DMODEL + h * HDIM + c0;
    short8 r0, r1;
#pragma unroll
    for (int i = 0; i < 8; ++i) {
        r0[i] = (short)f2bf(o[i] * inv);
        r1[i] = (short)f2bf(o[i + 8] * inv);
    }
    *(short8*)dst = r0;
    *(short8*)(dst + 8) = r1;
}

extern "C" void kernel_launch(void* const* d_in, const int* in_sizes, int n_in,
                              void* d_out, int out_size, void* d_ws, size_t ws_size,
                              hipStream_t stream) {
    const int*   tokens = (const int*)d_in[0];
    const float* emb    = (const float*)d_in[1];
    const float* pos    = (const float*)d_in[2];
    const float* mem    = (const float*)d_in[3];
    const float* ln1_s  = (const float*)d_in[4];
    const float* ln1_b  = (const float*)d_in[5];
    const float* wq     = (const float*)d_in[6];
    const float* wk     = (const float*)d_in[7];
    const float* wv     = (const float*)d_in[8];
    const float* wo     = (const float*)d_in[9];
    const float* ln2_s  = (const float*)d_in[10];
    const float* ln2_b  = (const float*)d_in[11];
    const float* w1     = (const float*)d_in[12];
    const float* b1     = (const float*)d_in[13];
    const float* w2     = (const float*)d_in[14];
    const float* b2     = (const float*)d_in[15];
    const float* lnm_s  = (const float*)d_in[16];
    const float* lnm_b  = (const float*)d_in[17];
    float* out = (float*)d_out;

    const int D = DMODEL, L = 4, FF = 4 * DMODEL, SP = SPAD;
    const int DD = D * D;
    const int DF = D * FF;
    const size_t PERL = (size_t)4 * DD + 2 * DF;   // bf16 elements per layer

    float*    x    = (float*)d_ws;
    ushort_t* qkvb = (ushort_t*)(x + (size_t)SP * D);
    ushort_t* nbuf = qkvb + (size_t)SP * 3 * D;
    ushort_t* attb = nbuf + (size_t)SP * D;
    ushort_t* ffh  = attb + (size_t)SP * D;
    ushort_t* wAll = ffh  + (size_t)SP * FF;       // 4 layers x PERL (~56.6 MB)
    // attention scratch overlays (dead regions during attention):
    ushort_t* Opart = ffh;
    float*    mlbuf = (float*)nbuf;

    embed_kernel<<<SP, 256, 0, stream>>>(tokens, emb, pos, mem, x);
    // all-layer weight convert, hoisted out of the layer loop
    cvt_all_kernel<<<(4 * (4 * DD + 2 * DF)) / 1024, 256, 0, stream>>>(
        wq, wk, wv, wo, w1, w2, wAll);

    dim3 gQKV(18, 17);      // N=2304          nk = 24
    dim3 gO(6, 17, 4);      // N=768, split-K  Kc=192 -> nk = 6
    dim3 gF1(24, 17);       // N=3072          nk = 24
    dim3 gF2(6, 17, 4);     // N=768, split-K  Kc=768 -> nk = 24
    dim3 gA(NQT, NHEAD, NZ);
    dim3 gC(NQT, NHEAD);

    for (int l = 0; l < L; ++l) {
        ushort_t* wqkv = wAll + (size_t)l * PERL;
        ushort_t* wob  = wqkv + (size_t)3 * DD;
        ushort_t* w1b  = wob  + (size_t)DD;
        ushort_t* w2b  = w1b  + (size_t)DF;

        ln_kernel<ushort_t><<<SP, 256, 0, stream>>>(x, ln1_s + l * D, ln1_b + l * D, nbuf);
        gemm_mfma<<<gQKV, 256, 0, stream>>>(nbuf, wqkv, nullptr, nullptr,
                                            qkvb, D, 3 * D, 0, 0, 1);
        attn_mfma<<<gA, 256, 0, stream>>>(qkvb, Opart, mlbuf);
        attn_combine<<<gC, 256, 0, stream>>>(Opart, mlbuf, attb);
        // split-K: x already holds the residual (h); partials atomicAdd in.
        gemm_mfma<<<gO, 256, 0, stream>>>(attb, wob, nullptr, nullptr,
                                          x, D, D, 0, 0, 0);
        ln_kernel<ushort_t><<<SP, 256, 0, stream>>>(x, ln2_s + l * D, ln2_b + l * D, nbuf);
        gemm_mfma<<<gF1, 256, 0, stream>>>(nbuf, w1b, b1 + (size_t)l * FF, nullptr,
                                           ffh, D, FF, 0, 1, 1);
        gemm_mfma<<<gF2, 256, 0, stream>>>(ffh, w2b, b2 + (size_t)l * D, nullptr,
                                           x, FF, D, 0, 0, 0);
    }
    ln_kernel<float><<<NMEM, 256, 0, stream>>>(x + (size_t)(S_TOT - NMEM) * D,
                                               lnm_s, lnm_b, out);
}

// Round 11
// 1001.292 us; speedup vs baseline: 1.0178x; 1.0178x over previous
//
#include <hip/hip_runtime.h>
#include <math.h>

#define S_TOT 2112
#define SPAD  2176   // 17 * 128
#define DMODEL 768
#define QKVLD 2304
#define NMEM 64
#define NHEAD 12
#define HDIM 64
#define NQT 33       // number of 64-row q tiles
#define CHUNK 9      // k-tiles per attention chunk
#define NZ 4         // max chunks = ceil(33/9)

typedef unsigned short ushort_t;
typedef __attribute__((ext_vector_type(8))) short short8;
typedef __attribute__((ext_vector_type(4))) float f32x4;

__device__ __forceinline__ ushort_t f2bf(float f) {
    unsigned int u = __builtin_bit_cast(unsigned int, f);
    u = (u + 0x7FFFu + ((u >> 16) & 1u)) >> 16;   // RNE
    return (ushort_t)u;
}
__device__ __forceinline__ float bf2f(ushort_t u) {
    unsigned int x = ((unsigned int)u) << 16;
    return __builtin_bit_cast(float, x);
}

// async global->LDS, 16B per lane (dwordx4). LDS dest is wave-uniform base +
// lane*16 (HW rule, m104); global src is per-lane (pre-swizzle goes here).
__device__ __forceinline__ void gl_lds16(const ushort_t* g, ushort_t* s) {
    __builtin_amdgcn_global_load_lds(
        (const __attribute__((address_space(1))) unsigned int*)g,
        (__attribute__((address_space(3))) unsigned int*)s,
        16, 0, 0);
}

// wait lgkmcnt(0) only — leave vmcnt/expcnt open
#define WAIT_LGKM() __builtin_amdgcn_s_waitcnt(0xC07F)
#define BAR()       __builtin_amdgcn_s_barrier()

// ---------------- f32 -> bf16 weight convert, ALL 4 LAYERS in one launch.
__global__ __launch_bounds__(256) void cvt_all_kernel(
    const float* __restrict__ wq, const float* __restrict__ wk,
    const float* __restrict__ wv, const float* __restrict__ wo,
    const float* __restrict__ w1, const float* __restrict__ w2,
    ushort_t* __restrict__ wAll)
{
    const int DD = DMODEL * DMODEL;               // 589824
    const int DF = DMODEL * 4 * DMODEL;           // 2359296
    const int DDv = DD / 4;                       // 147456
    const int DFv = DF / 4;                       // 589824
    const int PERLv = 4 * DDv + 2 * DFv;          // 1769472 vec4 per layer
    int i = blockIdx.x * 256 + threadIdx.x;
    int layer = i / PERLv;
    int r = i - layer * PERLv;
    const float* src;
    if (r < 3 * DDv) {
        if (r < DDv)          src = wq + (size_t)layer * DD + (size_t)r * 4;
        else if (r < 2 * DDv) src = wk + (size_t)layer * DD + (size_t)(r - DDv) * 4;
        else                  src = wv + (size_t)layer * DD + (size_t)(r - 2 * DDv) * 4;
    } else if (r < 4 * DDv) {
        src = wo + (size_t)layer * DD + (size_t)(r - 3 * DDv) * 4;
    } else if (r < 4 * DDv + DFv) {
        src = w1 + (size_t)layer * DF + (size_t)(r - 4 * DDv) * 4;
    } else {
        src = w2 + (size_t)layer * DF + (size_t)(r - 4 * DDv - DFv) * 4;
    }
    ushort_t* dst = wAll + (size_t)layer * PERLv * 4 + (size_t)r * 4;
    float4 v = *(const float4*)src;
    ushort4 o;
    o.x = f2bf(v.x); o.y = f2bf(v.y); o.z = f2bf(v.z); o.w = f2bf(v.w);
    *(ushort4*)dst = o;
}

// ---------------- embedding (pads rows >= S_TOT with zeros)
__global__ __launch_bounds__(256) void embed_kernel(
    const int* __restrict__ tokens, const float* __restrict__ emb,
    const float* __restrict__ pos, const float* __restrict__ mem,
    float* __restrict__ x)
{
    int s = blockIdx.x;
    int tid = threadIdx.x;
    float* xr = x + (size_t)s * DMODEL;
    if (s >= S_TOT) {
        for (int d = tid; d < DMODEL; d += 256) xr[d] = 0.0f;
    } else if (s < NMEM) {
        const float* mr = mem + (size_t)s * DMODEL;
        for (int d = tid; d < DMODEL; d += 256) xr[d] = mr[d];
    } else {
        int t = s - NMEM;
        int tok = tokens[t];
        const float* er = emb + (size_t)tok * DMODEL;
        const float* pr = pos + (size_t)t * DMODEL;
        for (int d = tid; d < DMODEL; d += 256) xr[d] = er[d] + pr[d];
    }
}

// ---------------- layernorm: wave-shuffle reduce, 2 barriers total
template <typename OUT>
__global__ __launch_bounds__(256) void ln_kernel(
    const float* __restrict__ X, const float* __restrict__ g,
    const float* __restrict__ b, OUT* __restrict__ Y)
{
    __shared__ float red[8];
    int row = blockIdx.x, tid = threadIdx.x;
    int wv = tid >> 6, ln = tid & 63;
    const float* xr = X + (size_t)row * DMODEL;
    float v0 = xr[tid], v1 = xr[tid + 256], v2 = xr[tid + 512];

    // pass 1: mean
    float s = v0 + v1 + v2;
#pragma unroll
    for (int off = 1; off < 64; off <<= 1) s += __shfl_xor(s, off);
    if (ln == 0) red[wv] = s;
    __syncthreads();
    float mu = (red[0] + red[1] + red[2] + red[3]) * (1.0f / 768.0f);

    // pass 2: variance of deviations
    float d0 = v0 - mu, d1 = v1 - mu, d2 = v2 - mu;
    float q = d0 * d0 + d1 * d1 + d2 * d2;
#pragma unroll
    for (int off = 1; off < 64; off <<= 1) q += __shfl_xor(q, off);
    if (ln == 0) red[4 + wv] = q;
    __syncthreads();
    float var = (red[4] + red[5] + red[6] + red[7]) * (1.0f / 768.0f);
    float inv = rsqrtf(var + 1e-5f);

    OUT* yr = Y + (size_t)row * DMODEL;
    float o0 = d0 * inv * g[tid]       + b[tid];
    float o1 = d1 * inv * g[tid + 256] + b[tid + 256];
    float o2 = d2 * inv * g[tid + 512] + b[tid + 512];
    if constexpr (sizeof(OUT) == 2) {
        yr[tid] = f2bf(o0); yr[tid + 256] = f2bf(o1); yr[tid + 512] = f2bf(o2);
    } else {
        yr[tid] = o0; yr[tid + 256] = o1; yr[tid + 512] = o2;
    }
}

// ---------------- bf16 MFMA GEMM: 4 waves (256 thr), 128x128 tile, BK=32,
// global_load_lds width=16 staging, THREE LDS buffers, counted-vmcnt pipeline
// (T3/T4): 3 tiles always in flight (12 outstanding gl_lds/wave); per step
// `s_waitcnt vmcnt(8)` guarantees only the OLDEST tile's 4 loads completed —
// vmcnt never drains to 0 in the loop (R10's regression was the vmcnt(0)
// drain inside __syncthreads). Raw s_barrier after the wait makes the tile
// visible to all waves; second (lgkm-only) barrier protects the buffer being
// restaged. Clamped redundant stages keep the 12-outstanding invariant so
// vmcnt(8) is always a precise oldest-tile wait; a restaged buffer is only
// ever one all waves just finished reading.
// Each wave owns a 64x64 sub-tile (acc[4][4]): 8 ds_read_b128 per 16 MFMAs.
// Swizzle per rule #21: LDS dest LINEAR, global SOURCE pre-swizzled
// chunk=(l&3)^((row>>1)&3), fragment reads use the matching XOR.
// 48 KB LDS -> 3 blocks/CU (__launch_bounds__(256,3)).
// C = act(A.B^T + bias) (+resid). A:[M,K] B:[N,K] bf16 row-major.
// XCD-bijective block swizzle. Split-K via gridDim.z (atomicAdd f32 partials).
__global__ __launch_bounds__(256, 3) void gemm_mfma(
    const ushort_t* __restrict__ A, const ushort_t* __restrict__ B,
    const float* __restrict__ bias, const float* __restrict__ resid,
    void* __restrict__ Cp, int K, int ldc, int ncol0, int act, int c_bf16)
{
    __shared__ ushort_t As[3][4096];   // 128 rows x 32 cols, 64 B/row
    __shared__ ushort_t Bs[3][4096];
    int tid = threadIdx.x;
    int l = tid & 63, w = tid >> 6;    // 4 waves
    int wr = w >> 1, wc = w & 1;       // each wave: 64x64 sub-tile

    // bijective XCD swizzle (m204) on the flattened (x,y) index; z untouched.
    int gx = gridDim.x;
    int nwg = gx * gridDim.y;
    int orig = blockIdx.x + gx * blockIdx.y;
    int q = nwg >> 3, r = nwg & 7;
    int xcd = orig & 7, loc = orig >> 3;
    int swz = (xcd < r ? xcd * (q + 1) : r * (q + 1) + (xcd - r) * q) + loc;
    int m0 = (swz / gx) * 128, n0 = (swz % gx) * 128;

    int kz = blockIdx.z;
    int nsplit = gridDim.z;
    int Kc = K / nsplit;              // multiple of 32 for all uses
    bool split = (nsplit > 1);

    // staging geometry: per wave, two 16-row sections each of A and B.
    int lrow = l >> 2;
    int r0 = w * 32, r1 = w * 32 + 16;
    int grow0 = r0 + lrow, grow1 = r1 + lrow;
    int gc0 = (l & 3) ^ ((grow0 >> 1) & 3);
    int gc1 = (l & 3) ^ ((grow1 >> 1) & 3);
    const ushort_t* ApS0 = A + (size_t)(m0 + grow0) * K + kz * Kc + gc0 * 8;
    const ushort_t* ApS1 = A + (size_t)(m0 + grow1) * K + kz * Kc + gc1 * 8;
    const ushort_t* BpS0 = B + (size_t)(n0 + grow0) * K + kz * Kc + gc0 * 8;
    const ushort_t* BpS1 = B + (size_t)(n0 + grow1) * K + kz * Kc + gc1 * 8;
    int lb0 = r0 * 32, lb1 = r1 * 32;  // wave-uniform LDS bases (ushort idx)

    // fragment LDS byte offsets (verified layout + matching XOR)
    int kc = l >> 4, mr = l & 15;
    int aoff[4], boff[4];
#pragma unroll
    for (int i = 0; i < 4; ++i) {
        int rr = wr * 64 + i * 16 + mr;
        aoff[i] = rr * 64 + ((kc ^ ((rr >> 1) & 3)) << 4);
        rr = wc * 64 + i * 16 + mr;
        boff[i] = rr * 64 + ((kc ^ ((rr >> 1) & 3)) << 4);
    }

    f32x4 acc[4][4];
#pragma unroll
    for (int i = 0; i < 4; ++i)
#pragma unroll
        for (int j = 0; j < 4; ++j)
            acc[i][j] = (f32x4){0.f, 0.f, 0.f, 0.f};

    int nk = Kc >> 5;                 // BK = 32

    auto stage = [&](int bi, int kt) {
        int ko = kt << 5;
        gl_lds16(ApS0 + ko, &As[bi][lb0]);
        gl_lds16(ApS1 + ko, &As[bi][lb1]);
        gl_lds16(BpS0 + ko, &Bs[bi][lb0]);
        gl_lds16(BpS1 + ko, &Bs[bi][lb1]);
    };

    // prologue: 3 tiles in flight (clamped for tiny nk)
    stage(0, 0);
    stage(1, 1 < nk ? 1 : nk - 1);
    stage(2, 2 < nk ? 2 : nk - 1);

    for (int k = 0; k < nk; ++k) {
        // oldest tile (k) complete: 12 outstanding -> wait <= 8
        asm volatile("s_waitcnt vmcnt(8)" ::: "memory");
        __builtin_amdgcn_sched_barrier(0);
        BAR();                         // tile k visible to all waves

        int bi = k - (k / 3) * 3;      // k % 3
        const char* bA = (const char*)As[bi];
        const char* bB = (const char*)Bs[bi];
        short8 af[4], bfr[4];
#pragma unroll
        for (int i = 0; i < 4; ++i) {
            af[i]  = *(const short8*)(bA + aoff[i]);
            bfr[i] = *(const short8*)(bB + boff[i]);
        }
#pragma unroll
        for (int i = 0; i < 4; ++i)
#pragma unroll
            for (int j = 0; j < 4; ++j)
                acc[i][j] = __builtin_amdgcn_mfma_f32_16x16x32_bf16(af[i], bfr[j], acc[i][j], 0, 0, 0);

        WAIT_LGKM();                   // own ds_reads retired
        BAR();                         // all waves done reading buf bi
        int t = k + 3;                 // restage buf bi (clamped, keeps
        if (t > nk - 1) t = nk - 1;    // 12-outstanding invariant)
        stage(bi, t);
    }

    // epilogue: D row = (l>>4)*4 + reg, col = l&15 (m89-verified)
    int lq = l >> 4;
#pragma unroll
    for (int i = 0; i < 4; ++i) {
#pragma unroll
        for (int rr = 0; rr < 4; ++rr) {
            int m = m0 + wr * 64 + i * 16 + lq * 4 + rr;
#pragma unroll
            for (int j = 0; j < 4; ++j) {
                int n = n0 + wc * 64 + j * 16 + mr;
                float v = acc[i][j][rr];
                if (bias && (!split || kz == 0)) v += bias[n];
                if (act) {
                    // tanh-GELU via sigmoid: 0.5u(1+tanh t) = u/(1+e^{-2t})
                    float u = v;
                    float t2 = 0.7978845608028654f * (u + 0.044715f * u * u * u);
                    v = u / (1.0f + __expf(-2.0f * t2));
                }
                size_t idx = (size_t)m * ldc + ncol0 + n;
                if (split) {
                    atomicAdd((float*)Cp + idx, v);
                } else {
                    if (resid) v += resid[idx];
                    if (c_bf16) ((ushort_t*)Cp)[idx] = f2bf(v);
                    else        ((float*)Cp)[idx] = v;
                }
            }
        }
    }
}

// ---------------- MFMA flash attention, chunked (flash-decode style).
__global__ __launch_bounds__(256) void attn_mfma(
    const ushort_t* __restrict__ qkv, ushort_t* __restrict__ Opart,
    float* __restrict__ ml)
{
    __shared__ ushort_t Qs[64][72];
    __shared__ ushort_t Ks[2][64][72];
    __shared__ ushort_t Vt[2][64][72];
    __shared__ ushort_t Ps[64][72];

    int qt = blockIdx.x;
    int h  = blockIdx.y;
    int z  = blockIdx.z;
    int kt0 = z * CHUNK;
    if (kt0 > qt) return;                       // inactive chunk (uniform exit)
    int kt1 = min(kt0 + CHUNK, qt + 1);

    int tid = threadIdx.x;
    int w = tid >> 6, lane = tid & 63;
    int quad = lane >> 4, l16 = lane & 15;
    int sr = lane;
    int dg = w;

    const size_t TSTRIDE = (size_t)64 * QKVLD;

    // stage Q tile
    {
        const ushort_t* qp = qkv + (size_t)(qt * 64 + sr) * QKVLD + h * HDIM + dg * 16;
        *(short8*)&Qs[sr][dg * 16]     = *(const short8*)qp;
        *(short8*)&Qs[sr][dg * 16 + 8] = *(const short8*)(qp + 8);
    }

    // prologue: tile kt0 -> regs -> buf0; tile kt0+1 -> regs (in flight).
    const ushort_t* kp = qkv + (size_t)(kt0 * 64 + sr) * QKVLD + DMODEL + h * HDIM + dg * 16;
    const ushort_t* vp = kp + DMODEL;
    short8 pk0 = *(const short8*)kp, pk1 = *(const short8*)(kp + 8);
    short8 pv0 = *(const short8*)vp, pv1 = *(const short8*)(vp + 8);
    kp += TSTRIDE; vp += TSTRIDE;

    *(short8*)&Ks[0][sr][dg * 16]     = pk0;
    *(short8*)&Ks[0][sr][dg * 16 + 8] = pk1;
#pragma unroll
    for (int j = 0; j < 8; ++j) Vt[0][dg * 16 + j][sr] = (ushort_t)pv0[j];
#pragma unroll
    for (int j = 0; j < 8; ++j) Vt[0][dg * 16 + 8 + j][sr] = (ushort_t)pv1[j];

    pk0 = *(const short8*)kp; pk1 = *(const short8*)(kp + 8);
    pv0 = *(const short8*)vp; pv1 = *(const short8*)(vp + 8);
    kp += TSTRIDE; vp += TSTRIDE;

    WAIT_LGKM(); BAR();

    short8 qf[2];
    qf[0] = *(const short8*)&Qs[w * 16 + l16][quad * 8];
    qf[1] = *(const short8*)&Qs[w * 16 + l16][32 + quad * 8];

    float mstate[4] = {-1e30f, -1e30f, -1e30f, -1e30f};
    float lstate[4] = {0.f, 0.f, 0.f, 0.f};
    f32x4 accO[4];
#pragma unroll
    for (int j = 0; j < 4; ++j) accO[j] = (f32x4){0.f, 0.f, 0.f, 0.f};

    for (int kt = kt0; kt < kt1; ++kt) {
        int cb = (kt - kt0) & 1;

        // QK^T on buffer cb
        f32x4 sacc[4];
#pragma unroll
        for (int nt = 0; nt < 4; ++nt) {
            sacc[nt] = (f32x4){0.f, 0.f, 0.f, 0.f};
            short8 kf0 = *(const short8*)&Ks[cb][nt * 16 + l16][quad * 8];
            short8 kf1 = *(const short8*)&Ks[cb][nt * 16 + l16][32 + quad * 8];
            sacc[nt] = __builtin_amdgcn_mfma_f32_16x16x32_bf16(qf[0], kf0, sacc[nt], 0, 0, 0);
            sacc[nt] = __builtin_amdgcn_mfma_f32_16x16x32_bf16(qf[1], kf1, sacc[nt], 0, 0, 0);
        }

        // commit prefetched tile kt+1 into the other buffer; issue loads kt+2.
        if (kt + 1 < kt1) {
            int nb = cb ^ 1;
            *(short8*)&Ks[nb][sr][dg * 16]     = pk0;
            *(short8*)&Ks[nb][sr][dg * 16 + 8] = pk1;
#pragma unroll
            for (int j = 0; j < 8; ++j) Vt[nb][dg * 16 + j][sr] = (ushort_t)pv0[j];
#pragma unroll
            for (int j = 0; j < 8; ++j) Vt[nb][dg * 16 + 8 + j][sr] = (ushort_t)pv1[j];
            pk0 = *(const short8*)kp; pk1 = *(const short8*)(kp + 8);
            pv0 = *(const short8*)vp; pv1 = *(const short8*)(vp + 8);
            kp += TSTRIDE; vp += TSTRIDE;
        }

        bool diag = (kt == qt);
        float s[4][4], rmax[4];
#pragma unroll
        for (int r = 0; r < 4; ++r) rmax[r] = -1e30f;
#pragma unroll
        for (int nt = 0; nt < 4; ++nt)
#pragma unroll
            for (int r = 0; r < 4; ++r) {
                float v = sacc[nt][r] * 0.125f;
                if (diag && (nt * 16 + l16) > (w * 16 + quad * 4 + r)) v = -1e30f;
                s[nt][r] = v;
                rmax[r] = fmaxf(rmax[r], v);
            }
#pragma unroll
        for (int r = 0; r < 4; ++r) {
            rmax[r] = fmaxf(rmax[r], __shfl_xor(rmax[r], 1));
            rmax[r] = fmaxf(rmax[r], __shfl_xor(rmax[r], 2));
            rmax[r] = fmaxf(rmax[r], __shfl_xor(rmax[r], 4));
            rmax[r] = fmaxf(rmax[r], __shfl_xor(rmax[r], 8));
        }
        float alpha[4];
#pragma unroll
        for (int r = 0; r < 4; ++r) {
            float mnew = fmaxf(mstate[r], rmax[r]);
            alpha[r] = __expf(mstate[r] - mnew);
            mstate[r] = mnew;
        }
        float rsum[4] = {0.f, 0.f, 0.f, 0.f};
#pragma unroll
        for (int nt = 0; nt < 4; ++nt)
#pragma unroll
            for (int r = 0; r < 4; ++r) {
                float p = __expf(s[nt][r] - mstate[r]);
                Ps[w * 16 + quad * 4 + r][nt * 16 + l16] = f2bf(p);
                rsum[r] += p;
            }
#pragma unroll
        for (int r = 0; r < 4; ++r) {
            rsum[r] += __shfl_xor(rsum[r], 1);
            rsum[r] += __shfl_xor(rsum[r], 2);
            rsum[r] += __shfl_xor(rsum[r], 4);
            rsum[r] += __shfl_xor(rsum[r], 8);
            lstate[r] = lstate[r] * alpha[r] + rsum[r];
        }
#pragma unroll
        for (int j = 0; j < 4; ++j)
#pragma unroll
            for (int r = 0; r < 4; ++r) accO[j][r] *= alpha[r];

        short8 pf0 = *(const short8*)&Ps[w * 16 + l16][quad * 8];
        short8 pf1 = *(const short8*)&Ps[w * 16 + l16][32 + quad * 8];
#pragma unroll
        for (int j = 0; j < 4; ++j) {
            short8 vf0 = *(const short8*)&Vt[cb][j * 16 + l16][quad * 8];
            short8 vf1 = *(const short8*)&Vt[cb][j * 16 + l16][32 + quad * 8];
            accO[j] = __builtin_amdgcn_mfma_f32_16x16x32_bf16(pf0, vf0, accO[j], 0, 0, 0);
            accO[j] = __builtin_amdgcn_mfma_f32_16x16x32_bf16(pf1, vf1, accO[j], 0, 0, 0);
        }

        WAIT_LGKM(); BAR();
    }

    // epilogue: write unnormalized partial numerator + (m,l) per row
    size_t pidx = (size_t)(h * NQT + qt) * NZ + z;
#pragma unroll
    for (int j = 0; j < 4; ++j)
#pragma unroll
        for (int r = 0; r < 4; ++r) {
            int row = w * 16 + quad * 4 + r;
            Opart[pidx * 4096 + row * 64 + j * 16 + l16] = f2bf(accO[j][r]);
        }
    if (l16 == 0) {
        float* mlr = ml + pidx * 128;
#pragma unroll
        for (int r = 0; r < 4; ++r) {
            int row = w * 16 + quad * 4 + r;
            mlr[row * 2]     = mstate[r];
            mlr[row * 2 + 1] = lstate[r];
        }
    }
}

// ---------------- merge attention chunks -> attb
__global__ __launch_bounds__(256) void attn_combine(
    const ushort_t* __restrict__ Opart, const float* __restrict__ ml,
    ushort_t* __restrict__ att)
{
    int qt = blockIdx.x, h = blockIdx.y;
    int nch = (qt + CHUNK) / CHUNK;   // ceil((qt+1)/CHUNK)
    int t = threadIdx.x;
    int row = t >> 2, c0 = (t & 3) << 4;
    size_t pb = (size_t)(h * NQT + qt) * NZ;

    float mv[NZ], lv[NZ];
    float M = -1e30f;
#pragma unroll
    for (int z = 0; z < NZ; ++z) {
        mv[z] = -1e30f; lv[z] = 0.f;
        if (z < nch) {
            const float* p = ml + (pb + z) * 128 + row * 2;
            mv[z] = p[0]; lv[z] = p[1];
            M = fmaxf(M, mv[z]);
        }
    }
    float denom = 0.f;
    float sc[NZ];
#pragma unroll
    for (int z = 0; z < NZ; ++z) {
        sc[z] = 0.f;
        if (z < nch) { sc[z] = __expf(mv[z] - M); denom += sc[z] * lv[z]; }
    }
    float inv = 1.0f / denom;

    float o[16];
#pragma unroll
    for (int i = 0; i < 16; ++i) o[i] = 0.f;
#pragma unroll
    for (int z = 0; z < NZ; ++z) {
        if (z < nch) {
            const ushort_t* op = Opart + (pb + z) * 4096 + row * 64 + c0;
            short8 a0 = *(const short8*)op;
            short8 a1 = *(const short8*)(op + 8);
#pragma unroll
            for (int i = 0; i < 8; ++i) o[i]     += sc[z] * bf2f((ushort_t)a0[i]);
#pragma unroll
            for (int i = 0; i < 8; ++i) o[i + 8] += sc[z] * bf2f((ushort_t)a1[i]);
        }
    }
    ushort_t* dst = att + (size_t)(qt * 64 + row) * DMODEL + h * HDIM + c0;
    short8 r0, r1;
#pragma unroll
    for (int i = 0; i < 8; ++i) {
        r0[i] = (short)f2bf(o[i] * inv);
        r1[i] = (short)f2bf(o[i + 8] * inv);
    }
    *(short8*)dst = r0;
    *(short8*)(dst + 8) = r1;
}

extern "C" void kernel_launch(void* const* d_in, const int* in_sizes, int n_in,
                              void* d_out, int out_size, void* d_ws, size_t ws_size,
                              hipStream_t stream) {
    const int*   tokens = (const int*)d_in[0];
    const float* emb    = (const float*)d_in[1];
    const float* pos    = (const float*)d_in[2];
    const float* mem    = (const float*)d_in[3];
    const float* ln1_s  = (const float*)d_in[4];
    const float* ln1_b  = (const float*)d_in[5];
    const float* wq     = (const float*)d_in[6];
    const float* wk     = (const float*)d_in[7];
    const float* wv     = (const float*)d_in[8];
    const float* wo     = (const float*)d_in[9];
    const float* ln2_s  = (const float*)d_in[10];
    const float* ln2_b  = (const float*)d_in[11];
    const float* w1     = (const float*)d_in[12];
    const float* b1     = (const float*)d_in[13];
    const float* w2     = (const float*)d_in[14];
    const float* b2     = (const float*)d_in[15];
    const float* lnm_s  = (const float*)d_in[16];
    const float* lnm_b  = (const float*)d_in[17];
    float* out = (float*)d_out;

    const int D = DMODEL, L = 4, FF = 4 * DMODEL, SP = SPAD;
    const int DD = D * D;
    const int DF = D * FF;
    const size_t PERL = (size_t)4 * DD + 2 * DF;   // bf16 elements per layer

    float*    x    = (float*)d_ws;
    ushort_t* qkvb = (ushort_t*)(x + (size_t)SP * D);
    ushort_t* nbuf = qkvb + (size_t)SP * 3 * D;
    ushort_t* attb = nbuf + (size_t)SP * D;
    ushort_t* ffh  = attb + (size_t)SP * D;
    ushort_t* wAll = ffh  + (size_t)SP * FF;       // 4 layers x PERL (~56.6 MB)
    // attention scratch overlays (dead regions during attention):
    ushort_t* Opart = ffh;
    float*    mlbuf = (float*)nbuf;

    embed_kernel<<<SP, 256, 0, stream>>>(tokens, emb, pos, mem, x);
    // all-layer weight convert, hoisted out of the layer loop
    cvt_all_kernel<<<(4 * (4 * DD + 2 * DF)) / 1024, 256, 0, stream>>>(
        wq, wk, wv, wo, w1, w2, wAll);

    dim3 gQKV(18, 17);      // N=2304          nk = 24
    dim3 gO(6, 17, 4);      // N=768, split-K  Kc=192 -> nk = 6
    dim3 gF1(24, 17);       // N=3072          nk = 24
    dim3 gF2(6, 17, 4);     // N=768, split-K  Kc=768 -> nk = 24
    dim3 gA(NQT, NHEAD, NZ);
    dim3 gC(NQT, NHEAD);

    for (int l = 0; l < L; ++l) {
        ushort_t* wqkv = wAll + (size_t)l * PERL;
        ushort_t* wob  = wqkv + (size_t)3 * DD;
        ushort_t* w1b  = wob  + (size_t)DD;
        ushort_t* w2b  = w1b  + (size_t)DF;

        ln_kernel<ushort_t><<<SP, 256, 0, stream>>>(x, ln1_s + l * D, ln1_b + l * D, nbuf);
        gemm_mfma<<<gQKV, 256, 0, stream>>>(nbuf, wqkv, nullptr, nullptr,
                                            qkvb, D, 3 * D, 0, 0, 1);
        attn_mfma<<<gA, 256, 0, stream>>>(qkvb, Opart, mlbuf);
        attn_combine<<<gC, 256, 0, stream>>>(Opart, mlbuf, attb);
        // split-K: x already holds the residual (h); partials atomicAdd in.
        gemm_mfma<<<gO, 256, 0, stream>>>(attb, wob, nullptr, nullptr,
                                          x, D, D, 0, 0, 0);
        ln_kernel<ushort_t><<<SP, 256, 0, stream>>>(x, ln2_s + l * D, ln2_b + l * D, nbuf);
        gemm_mfma<<<gF1, 256, 0, stream>>>(nbuf, w1b, b1 + (size_t)l * FF, nullptr,
                                           ffh, D, FF, 0, 1, 1);
        gemm_mfma<<<gF2, 256, 0, stream>>>(ffh, w2b, b2 + (size_t)l * D, nullptr,
                                           x, FF, D, 0, 0, 0);
    }
    ln_kernel<float><<<NMEM, 256, 0, stream>>>(x + (size_t)(S_TOT - NMEM) * D,
                                               lnm_s, lnm_b, out);
}

// Round 13
// 878.746 us; speedup vs baseline: 1.1598x; 1.1395x over previous
//
#include <hip/hip_runtime.h>
#include <math.h>

#define S_TOT 2112
#define SPAD  2176   // 17 * 128
#define DMODEL 768
#define QKVLD 2304
#define NMEM 64
#define NHEAD 12
#define HDIM 64
#define NQT 33       // number of 64-row q tiles
#define CHUNK 6      // k-tiles per attention chunk
#define NZ 6         // max chunks = ceil(33/6)

typedef unsigned short ushort_t;
typedef __attribute__((ext_vector_type(8))) short short8;
typedef __attribute__((ext_vector_type(4))) float f32x4;

__device__ __forceinline__ ushort_t f2bf(float f) {
    unsigned int u = __builtin_bit_cast(unsigned int, f);
    u = (u + 0x7FFFu + ((u >> 16) & 1u)) >> 16;   // RNE
    return (ushort_t)u;
}
__device__ __forceinline__ float bf2f(ushort_t u) {
    unsigned int x = ((unsigned int)u) << 16;
    return __builtin_bit_cast(float, x);
}

// wait lgkmcnt(0) only — leave vmcnt/expcnt open so prefetch loads stay in flight
#define WAIT_LGKM() __builtin_amdgcn_s_waitcnt(0xC07F)
#define BAR()       __builtin_amdgcn_s_barrier()

// ---------------- f32 -> bf16 weight convert, ALL 4 LAYERS in one launch.
// Per-layer dst layout: [wqkv 3DD | wob DD | w1b DF | w2b DF], stride PERL.
__global__ __launch_bounds__(256) void cvt_all_kernel(
    const float* __restrict__ wq, const float* __restrict__ wk,
    const float* __restrict__ wv, const float* __restrict__ wo,
    const float* __restrict__ w1, const float* __restrict__ w2,
    ushort_t* __restrict__ wAll)
{
    const int DD = DMODEL * DMODEL;               // 589824
    const int DF = DMODEL * 4 * DMODEL;           // 2359296
    const int DDv = DD / 4;                       // 147456
    const int DFv = DF / 4;                       // 589824
    const int PERLv = 4 * DDv + 2 * DFv;          // 1769472 vec4 per layer
    int i = blockIdx.x * 256 + threadIdx.x;
    int layer = i / PERLv;
    int r = i - layer * PERLv;
    const float* src;
    if (r < 3 * DDv) {
        if (r < DDv)          src = wq + (size_t)layer * DD + (size_t)r * 4;
        else if (r < 2 * DDv) src = wk + (size_t)layer * DD + (size_t)(r - DDv) * 4;
        else                  src = wv + (size_t)layer * DD + (size_t)(r - 2 * DDv) * 4;
    } else if (r < 4 * DDv) {
        src = wo + (size_t)layer * DD + (size_t)(r - 3 * DDv) * 4;
    } else if (r < 4 * DDv + DFv) {
        src = w1 + (size_t)layer * DF + (size_t)(r - 4 * DDv) * 4;
    } else {
        src = w2 + (size_t)layer * DF + (size_t)(r - 4 * DDv - DFv) * 4;
    }
    ushort_t* dst = wAll + (size_t)layer * PERLv * 4 + (size_t)r * 4;
    float4 v = *(const float4*)src;
    ushort4 o;
    o.x = f2bf(v.x); o.y = f2bf(v.y); o.z = f2bf(v.z); o.w = f2bf(v.w);
    *(ushort4*)dst = o;
}

// ---------------- embedding (pads rows >= S_TOT with zeros)
__global__ __launch_bounds__(256) void embed_kernel(
    const int* __restrict__ tokens, const float* __restrict__ emb,
    const float* __restrict__ pos, const float* __restrict__ mem,
    float* __restrict__ x)
{
    int s = blockIdx.x;
    int tid = threadIdx.x;
    float* xr = x + (size_t)s * DMODEL;
    if (s >= S_TOT) {
        for (int d = tid; d < DMODEL; d += 256) xr[d] = 0.0f;
    } else if (s < NMEM) {
        const float* mr = mem + (size_t)s * DMODEL;
        for (int d = tid; d < DMODEL; d += 256) xr[d] = mr[d];
    } else {
        int t = s - NMEM;
        int tok = tokens[t];
        const float* er = emb + (size_t)tok * DMODEL;
        const float* pr = pos + (size_t)t * DMODEL;
        for (int d = tid; d < DMODEL; d += 256) xr[d] = er[d] + pr[d];
    }
}

// ---------------- layernorm: wave-shuffle reduce, 2 barriers total
template <typename OUT>
__global__ __launch_bounds__(256) void ln_kernel(
    const float* __restrict__ X, const float* __restrict__ g,
    const float* __restrict__ b, OUT* __restrict__ Y)
{
    __shared__ float red[8];
    int row = blockIdx.x, tid = threadIdx.x;
    int wv = tid >> 6, ln = tid & 63;
    const float* xr = X + (size_t)row * DMODEL;
    float v0 = xr[tid], v1 = xr[tid + 256], v2 = xr[tid + 512];

    // pass 1: mean
    float s = v0 + v1 + v2;
#pragma unroll
    for (int off = 1; off < 64; off <<= 1) s += __shfl_xor(s, off);
    if (ln == 0) red[wv] = s;
    __syncthreads();
    float mu = (red[0] + red[1] + red[2] + red[3]) * (1.0f / 768.0f);

    // pass 2: variance of deviations
    float d0 = v0 - mu, d1 = v1 - mu, d2 = v2 - mu;
    float q = d0 * d0 + d1 * d1 + d2 * d2;
#pragma unroll
    for (int off = 1; off < 64; off <<= 1) q += __shfl_xor(q, off);
    if (ln == 0) red[4 + wv] = q;
    __syncthreads();
    float var = (red[4] + red[5] + red[6] + red[7]) * (1.0f / 768.0f);
    float inv = rsqrtf(var + 1e-5f);

    OUT* yr = Y + (size_t)row * DMODEL;
    float o0 = d0 * inv * g[tid]       + b[tid];
    float o1 = d1 * inv * g[tid + 256] + b[tid + 256];
    float o2 = d2 * inv * g[tid + 512] + b[tid + 512];
    if constexpr (sizeof(OUT) == 2) {
        yr[tid] = f2bf(o0); yr[tid + 256] = f2bf(o1); yr[tid + 512] = f2bf(o2);
    } else {
        yr[tid] = o0; yr[tid + 256] = o1; yr[tid + 512] = o2;
    }
}

// ---------------- bf16 MFMA GEMM, 8-wave (512-thread) 128x128 tile, BK=64,
// depth-2 register-prefetch double-buffered pipeline (R9-verified best).
// One lgkm-only barrier per 64-K step; per step each wave does 16 MFMAs
// and 12 ds_read_b128s. LDS rows are 128 B -> G4 XOR swizzle byte^=(row&7)<<4
// on write AND read. __launch_bounds__(512, 4) caps VGPR for 2 blocks/CU.
// C = act(A.B^T + bias) (+resid). A:[M,K] B:[N,K] bf16 row-major.
// 8 waves = 4 row-groups x 2 col-groups, each wave a 32x64 sub-tile acc[2][4].
// XCD-bijective block swizzle. Split-K via gridDim.z (atomicAdd f32 partials).
// Requires nk >= 3 (call sites: nk = 3 or 12).
__global__ __launch_bounds__(512, 4) void gemm_mfma(
    const ushort_t* __restrict__ A, const ushort_t* __restrict__ B,
    const float* __restrict__ bias, const float* __restrict__ resid,
    void* __restrict__ Cp, int K, int ldc, int ncol0, int act, int c_bf16)
{
    __shared__ ushort_t As[2][8192];   // 128 rows x 64 cols, 128 B/row
    __shared__ ushort_t Bs[2][8192];
    int tid = threadIdx.x;
    int l = tid & 63, w = tid >> 6;    // 8 waves
    int wr = w >> 1, wc = w & 1;       // wr in [0,4), wc in [0,2)

    // bijective XCD swizzle (m204) on the flattened (x,y) index; z untouched.
    int gx = gridDim.x;
    int nwg = gx * gridDim.y;
    int orig = blockIdx.x + gx * blockIdx.y;
    int q = nwg >> 3, r = nwg & 7;
    int xcd = orig & 7, loc = orig >> 3;
    int swz = (xcd < r ? xcd * (q + 1) : r * (q + 1) + (xcd - r) * q) + loc;
    int m0 = (swz / gx) * 128, n0 = (swz % gx) * 128;

    int kz = blockIdx.z;
    int nsplit = gridDim.z;
    int Kc = K / nsplit;              // multiple of 64 for all uses
    bool split = (nsplit > 1);

    // staging: thread covers row = tid>>2, chunks g and g+4 (16 B each).
    int row = tid >> 2, g = tid & 3;
    int sw0 = row * 128 + (((g)     ^ (row & 7)) << 4);
    int sw1 = row * 128 + (((g + 4) ^ (row & 7)) << 4);
    const ushort_t* Ap = A + (size_t)(m0 + row) * K + kz * Kc;
    const ushort_t* Bp = B + (size_t)(n0 + row) * K + kz * Kc;
    int go0 = g * 8, go1 = (g + 4) * 8;   // element offsets within a 64-col tile

    // fragment LDS byte offsets: logical chunk c = kc + 4*kh of row rr
    int kc = l >> 4, mr = l & 15;
    int aoff[2][2], boff[4][2];
#pragma unroll
    for (int i = 0; i < 2; ++i) {
        int rr = wr * 32 + i * 16 + mr;
#pragma unroll
        for (int kh = 0; kh < 2; ++kh)
            aoff[i][kh] = rr * 128 + (((kc + 4 * kh) ^ (rr & 7)) << 4);
    }
#pragma unroll
    for (int j = 0; j < 4; ++j) {
        int rr = wc * 64 + j * 16 + mr;
#pragma unroll
        for (int kh = 0; kh < 2; ++kh)
            boff[j][kh] = rr * 128 + (((kc + 4 * kh) ^ (rr & 7)) << 4);
    }

    f32x4 acc[2][4];
#pragma unroll
    for (int i = 0; i < 2; ++i)
#pragma unroll
        for (int j = 0; j < 4; ++j)
            acc[i][j] = (f32x4){0.f, 0.f, 0.f, 0.f};

    int nk = Kc >> 6;                 // BK = 64

    auto kstep = [&](int bi) {
        const char* bA = (const char*)As[bi];
        const char* bB = (const char*)Bs[bi];
        short8 af[2][2], bfr[4][2];
#pragma unroll
        for (int i = 0; i < 2; ++i)
#pragma unroll
            for (int kh = 0; kh < 2; ++kh)
                af[i][kh] = *(const short8*)(bA + aoff[i][kh]);
#pragma unroll
        for (int j = 0; j < 4; ++j)
#pragma unroll
            for (int kh = 0; kh < 2; ++kh)
                bfr[j][kh] = *(const short8*)(bB + boff[j][kh]);
#pragma unroll
        for (int kh = 0; kh < 2; ++kh)
#pragma unroll
            for (int i = 0; i < 2; ++i)
#pragma unroll
                for (int j = 0; j < 4; ++j)
                    acc[i][j] = __builtin_amdgcn_mfma_f32_16x16x32_bf16(af[i][kh], bfr[j][kh], acc[i][j], 0, 0, 0);
    };
    // commit a reg set -> LDS buf bi, then refill the set with tile t (clamped;
    // redundant refills are L2 hits and never committed).
    auto commit = [&](short8& a0, short8& a1, short8& b0, short8& b1, int bi, int t) {
        *(short8*)((char*)As[bi] + sw0) = a0;
        *(short8*)((char*)As[bi] + sw1) = a1;
        *(short8*)((char*)Bs[bi] + sw0) = b0;
        *(short8*)((char*)Bs[bi] + sw1) = b1;
        int ko = (t < nk ? t : nk - 1) << 6;
        a0 = *(const short8*)(Ap + ko + go0);
        a1 = *(const short8*)(Ap + ko + go1);
        b0 = *(const short8*)(Bp + ko + go0);
        b1 = *(const short8*)(Bp + ko + go1);
    };

    // prologue: tile0 -> LDS buf0 (blocking); tile1 -> odd set; tile2 -> even.
    {
        short8 a0 = *(const short8*)(Ap + go0);
        short8 a1 = *(const short8*)(Ap + go1);
        short8 b0 = *(const short8*)(Bp + go0);
        short8 b1 = *(const short8*)(Bp + go1);
        *(short8*)((char*)As[0] + sw0) = a0;
        *(short8*)((char*)As[0] + sw1) = a1;
        *(short8*)((char*)Bs[0] + sw0) = b0;
        *(short8*)((char*)Bs[0] + sw1) = b1;
    }
    short8 oa0 = *(const short8*)(Ap + 64 + go0), oa1 = *(const short8*)(Ap + 64 + go1);
    short8 ob0 = *(const short8*)(Bp + 64 + go0), ob1 = *(const short8*)(Bp + 64 + go1);
    short8 ea0 = *(const short8*)(Ap + 128 + go0), ea1 = *(const short8*)(Ap + 128 + go1);
    short8 eb0 = *(const short8*)(Bp + 128 + go0), eb1 = *(const short8*)(Bp + 128 + go1);
    WAIT_LGKM(); BAR();

    for (int k = 0; k < nk; k += 2) {
        // even step k: compute buf0; commit odd set (tile k+1) -> buf1
        kstep(0);
        if (k + 1 < nk) commit(oa0, oa1, ob0, ob1, 1, k + 3);
        WAIT_LGKM(); BAR();
        // odd step k+1: compute buf1; commit even set (tile k+2) -> buf0
        if (k + 1 < nk) {
            kstep(1);
            if (k + 2 < nk) commit(ea0, ea1, eb0, eb1, 0, k + 4);
            WAIT_LGKM(); BAR();
        }
    }

    // epilogue: D row = (l>>4)*4 + reg, col = l&15 (m89-verified)
    int lq = l >> 4;
#pragma unroll
    for (int i = 0; i < 2; ++i) {
#pragma unroll
        for (int rr = 0; rr < 4; ++rr) {
            int m = m0 + wr * 32 + i * 16 + lq * 4 + rr;
#pragma unroll
            for (int j = 0; j < 4; ++j) {
                int n = n0 + wc * 64 + j * 16 + mr;
                float v = acc[i][j][rr];
                if (bias && (!split || kz == 0)) v += bias[n];
                if (act) {
                    // tanh-GELU via sigmoid: 0.5u(1+tanh t) = u/(1+e^{-2t})
                    float u = v;
                    float t = 0.7978845608028654f * (u + 0.044715f * u * u * u);
                    v = u / (1.0f + __expf(-2.0f * t));
                }
                size_t idx = (size_t)m * ldc + ncol0 + n;
                if (split) {
                    atomicAdd((float*)Cp + idx, v);
                } else {
                    if (resid) v += resid[idx];
                    if (c_bf16) ((ushort_t*)Cp)[idx] = f2bf(v);
                    else        ((float*)Cp)[idx] = v;
                }
            }
        }
    }
}

// ---------------- MFMA flash attention, chunked (flash-decode style).
// Block = (q-tile, head, k-chunk of CHUNK tiles), 4 waves. Each chunk runs the
// double-buffered flash inner loop over its k-range and writes an UNNORMALIZED
// partial numerator (bf16) + per-row (m,l) to scratch; attn_combine merges.
// CHUNK=6 (was 9): critical path 33% shorter, active blocks 936->1296.
__global__ __launch_bounds__(256) void attn_mfma(
    const ushort_t* __restrict__ qkv, ushort_t* __restrict__ Opart,
    float* __restrict__ ml)
{
    __shared__ ushort_t Qs[64][72];
    __shared__ ushort_t Ks[2][64][72];
    __shared__ ushort_t Vt[2][64][72];
    __shared__ ushort_t Ps[64][72];

    int qt = blockIdx.x;
    int h  = blockIdx.y;
    int z  = blockIdx.z;
    int kt0 = z * CHUNK;
    if (kt0 > qt) return;                       // inactive chunk (uniform exit)
    int kt1 = min(kt0 + CHUNK, qt + 1);

    int tid = threadIdx.x;
    int w = tid >> 6, lane = tid & 63;
    int quad = lane >> 4, l16 = lane & 15;
    int sr = lane;
    int dg = w;

    const size_t TSTRIDE = (size_t)64 * QKVLD;

    // stage Q tile
    {
        const ushort_t* qp = qkv + (size_t)(qt * 64 + sr) * QKVLD + h * HDIM + dg * 16;
        *(short8*)&Qs[sr][dg * 16]     = *(const short8*)qp;
        *(short8*)&Qs[sr][dg * 16 + 8] = *(const short8*)(qp + 8);
    }

    // prologue: tile kt0 -> regs -> buf0; tile kt0+1 -> regs (in flight).
    const ushort_t* kp = qkv + (size_t)(kt0 * 64 + sr) * QKVLD + DMODEL + h * HDIM + dg * 16;
    const ushort_t* vp = kp + DMODEL;
    short8 pk0 = *(const short8*)kp, pk1 = *(const short8*)(kp + 8);
    short8 pv0 = *(const short8*)vp, pv1 = *(const short8*)(vp + 8);
    kp += TSTRIDE; vp += TSTRIDE;

    *(short8*)&Ks[0][sr][dg * 16]     = pk0;
    *(short8*)&Ks[0][sr][dg * 16 + 8] = pk1;
#pragma unroll
    for (int j = 0; j < 8; ++j) Vt[0][dg * 16 + j][sr] = (ushort_t)pv0[j];
#pragma unroll
    for (int j = 0; j < 8; ++j) Vt[0][dg * 16 + 8 + j][sr] = (ushort_t)pv1[j];

    pk0 = *(const short8*)kp; pk1 = *(const short8*)(kp + 8);
    pv0 = *(const short8*)vp; pv1 = *(const short8*)(vp + 8);
    kp += TSTRIDE; vp += TSTRIDE;

    WAIT_LGKM(); BAR();

    short8 qf[2];
    qf[0] = *(const short8*)&Qs[w * 16 + l16][quad * 8];
    qf[1] = *(const short8*)&Qs[w * 16 + l16][32 + quad * 8];

    float mstate[4] = {-1e30f, -1e30f, -1e30f, -1e30f};
    float lstate[4] = {0.f, 0.f, 0.f, 0.f};
    f32x4 accO[4];
#pragma unroll
    for (int j = 0; j < 4; ++j) accO[j] = (f32x4){0.f, 0.f, 0.f, 0.f};

    for (int kt = kt0; kt < kt1; ++kt) {
        int cb = (kt - kt0) & 1;

        // QK^T on buffer cb
        f32x4 sacc[4];
#pragma unroll
        for (int nt = 0; nt < 4; ++nt) {
            sacc[nt] = (f32x4){0.f, 0.f, 0.f, 0.f};
            short8 kf0 = *(const short8*)&Ks[cb][nt * 16 + l16][quad * 8];
            short8 kf1 = *(const short8*)&Ks[cb][nt * 16 + l16][32 + quad * 8];
            sacc[nt] = __builtin_amdgcn_mfma_f32_16x16x32_bf16(qf[0], kf0, sacc[nt], 0, 0, 0);
            sacc[nt] = __builtin_amdgcn_mfma_f32_16x16x32_bf16(qf[1], kf1, sacc[nt], 0, 0, 0);
        }

        // commit prefetched tile kt+1 into the other buffer; issue loads kt+2.
        if (kt + 1 < kt1) {
            int nb = cb ^ 1;
            *(short8*)&Ks[nb][sr][dg * 16]     = pk0;
            *(short8*)&Ks[nb][sr][dg * 16 + 8] = pk1;
#pragma unroll
            for (int j = 0; j < 8; ++j) Vt[nb][dg * 16 + j][sr] = (ushort_t)pv0[j];
#pragma unroll
            for (int j = 0; j < 8; ++j) Vt[nb][dg * 16 + 8 + j][sr] = (ushort_t)pv1[j];
            pk0 = *(const short8*)kp; pk1 = *(const short8*)(kp + 8);
            pv0 = *(const short8*)vp; pv1 = *(const short8*)(vp + 8);
            kp += TSTRIDE; vp += TSTRIDE;
        }

        bool diag = (kt == qt);
        float s[4][4], rmax[4];
#pragma unroll
        for (int r = 0; r < 4; ++r) rmax[r] = -1e30f;
#pragma unroll
        for (int nt = 0; nt < 4; ++nt)
#pragma unroll
            for (int r = 0; r < 4; ++r) {
                float v = sacc[nt][r] * 0.125f;
                if (diag && (nt * 16 + l16) > (w * 16 + quad * 4 + r)) v = -1e30f;
                s[nt][r] = v;
                rmax[r] = fmaxf(rmax[r], v);
            }
#pragma unroll
        for (int r = 0; r < 4; ++r) {
            rmax[r] = fmaxf(rmax[r], __shfl_xor(rmax[r], 1));
            rmax[r] = fmaxf(rmax[r], __shfl_xor(rmax[r], 2));
            rmax[r] = fmaxf(rmax[r], __shfl_xor(rmax[r], 4));
            rmax[r] = fmaxf(rmax[r], __shfl_xor(rmax[r], 8));
        }
        float alpha[4];
#pragma unroll
        for (int r = 0; r < 4; ++r) {
            float mnew = fmaxf(mstate[r], rmax[r]);
            alpha[r] = __expf(mstate[r] - mnew);
            mstate[r] = mnew;
        }
        float rsum[4] = {0.f, 0.f, 0.f, 0.f};
#pragma unroll
        for (int nt = 0; nt < 4; ++nt)
#pragma unroll
            for (int r = 0; r < 4; ++r) {
                float p = __expf(s[nt][r] - mstate[r]);
                Ps[w * 16 + quad * 4 + r][nt * 16 + l16] = f2bf(p);
                rsum[r] += p;
            }
#pragma unroll
        for (int r = 0; r < 4; ++r) {
            rsum[r] += __shfl_xor(rsum[r], 1);
            rsum[r] += __shfl_xor(rsum[r], 2);
            rsum[r] += __shfl_xor(rsum[r], 4);
            rsum[r] += __shfl_xor(rsum[r], 8);
            lstate[r] = lstate[r] * alpha[r] + rsum[r];
        }
#pragma unroll
        for (int j = 0; j < 4; ++j)
#pragma unroll
            for (int r = 0; r < 4; ++r) accO[j][r] *= alpha[r];

        short8 pf0 = *(const short8*)&Ps[w * 16 + l16][quad * 8];
        short8 pf1 = *(const short8*)&Ps[w * 16 + l16][32 + quad * 8];
#pragma unroll
        for (int j = 0; j < 4; ++j) {
            short8 vf0 = *(const short8*)&Vt[cb][j * 16 + l16][quad * 8];
            short8 vf1 = *(const short8*)&Vt[cb][j * 16 + l16][32 + quad * 8];
            accO[j] = __builtin_amdgcn_mfma_f32_16x16x32_bf16(pf0, vf0, accO[j], 0, 0, 0);
            accO[j] = __builtin_amdgcn_mfma_f32_16x16x32_bf16(pf1, vf1, accO[j], 0, 0, 0);
        }

        WAIT_LGKM(); BAR();
    }

    // epilogue: write unnormalized partial numerator + (m,l) per row
    size_t pidx = (size_t)(h * NQT + qt) * NZ + z;
#pragma unroll
    for (int j = 0; j < 4; ++j)
#pragma unroll
        for (int r = 0; r < 4; ++r) {
            int row = w * 16 + quad * 4 + r;
            Opart[pidx * 4096 + row * 64 + j * 16 + l16] = f2bf(accO[j][r]);
        }
    if (l16 == 0) {
        float* mlr = ml + pidx * 128;
#pragma unroll
        for (int r = 0; r < 4; ++r) {
            int row = w * 16 + quad * 4 + r;
            mlr[row * 2]     = mstate[r];
            mlr[row * 2 + 1] = lstate[r];
        }
    }
}

// ---------------- merge attention chunks -> attb
__global__ __launch_bounds__(256) void attn_combine(
    const ushort_t* __restrict__ Opart, const float* __restrict__ ml,
    ushort_t* __restrict__ att)
{
    int qt = blockIdx.x, h = blockIdx.y;
    int nch = (qt + CHUNK) / CHUNK;   // ceil((qt+1)/CHUNK)
    int t = threadIdx.x;
    int row = t >> 2, c0 = (t & 3) << 4;
    size_t pb = (size_t)(h * NQT + qt) * NZ;

    float mv[NZ], lv[NZ];
    float M = -1e30f;
#pragma unroll
    for (int z = 0; z < NZ; ++z) {
        mv[z] = -1e30f; lv[z] = 0.f;
        if (z < nch) {
            const float* p = ml + (pb + z) * 128 + row * 2;
            mv[z] = p[0]; lv[z] = p[1];
            M = fmaxf(M, mv[z]);
        }
    }
    float denom = 0.f;
    float sc[NZ];
#pragma unroll
    for (int z = 0; z < NZ; ++z) {
        sc[z] = 0.f;
        if (z < nch) { sc[z] = __expf(mv[z] - M); denom += sc[z] * lv[z]; }
    }
    float inv = 1.0f / denom;

    float o[16];
#pragma unroll
    for (int i = 0; i < 16; ++i) o[i] = 0.f;
#pragma unroll
    for (int z = 0; z < NZ; ++z) {
        if (z < nch) {
            const ushort_t* op = Opart + (pb + z) * 4096 + row * 64 + c0;
            short8 a0 = *(const short8*)op;
            short8 a1 = *(const short8*)(op + 8);
#pragma unroll
            for (int i = 0; i < 8; ++i) o[i]     += sc[z] * bf2f((ushort_t)a0[i]);
#pragma unroll
            for (int i = 0; i < 8; ++i) o[i + 8] += sc[z] * bf2f((ushort_t)a1[i]);
        }
    }
    ushort_t* dst = att + (size_t)(qt * 64 + row) * DMODEL + h * HDIM + c0;
    short8 r0, r1;
#pragma unroll
    for (int i = 0; i < 8; ++i) {
        r0[i] = (short)f2bf(o[i] * inv);
        r1[i] = (short)f2bf(o[i + 8] * inv);
    }
    *(short8*)dst = r0;
    *(short8*)(dst + 8) = r1;
}

extern "C" void kernel_launch(void* const* d_in, const int* in_sizes, int n_in,
                              void* d_out, int out_size, void* d_ws, size_t ws_size,
                              hipStream_t stream) {
    const int*   tokens = (const int*)d_in[0];
    const float* emb    = (const float*)d_in[1];
    const float* pos    = (const float*)d_in[2];
    const float* mem    = (const float*)d_in[3];
    const float* ln1_s  = (const float*)d_in[4];
    const float* ln1_b  = (const float*)d_in[5];
    const float* wq     = (const float*)d_in[6];
    const float* wk     = (const float*)d_in[7];
    const float* wv     = (const float*)d_in[8];
    const float* wo     = (const float*)d_in[9];
    const float* ln2_s  = (const float*)d_in[10];
    const float* ln2_b  = (const float*)d_in[11];
    const float* w1     = (const float*)d_in[12];
    const float* b1     = (const float*)d_in[13];
    const float* w2     = (const float*)d_in[14];
    const float* b2     = (const float*)d_in[15];
    const float* lnm_s  = (const float*)d_in[16];
    const float* lnm_b  = (const float*)d_in[17];
    float* out = (float*)d_out;

    const int D = DMODEL, L = 4, FF = 4 * DMODEL, SP = SPAD;
    const int DD = D * D;
    const int DF = D * FF;
    const size_t PERL = (size_t)4 * DD + 2 * DF;   // bf16 elements per layer

    float*    x    = (float*)d_ws;
    ushort_t* qkvb = (ushort_t*)(x + (size_t)SP * D);
    ushort_t* nbuf = qkvb + (size_t)SP * 3 * D;
    ushort_t* attb = nbuf + (size_t)SP * D;
    ushort_t* ffh  = attb + (size_t)SP * D;
    ushort_t* wAll = ffh  + (size_t)SP * FF;       // 4 layers x PERL (~56.6 MB)
    // dedicated attention scratch (after weights; no overlay aliasing):
    ushort_t* Opart = wAll + (size_t)4 * PERL;     // 12*33*NZ*4096*2B ~ 19.5 MB
    float*    mlbuf = (float*)(Opart + (size_t)NHEAD * NQT * NZ * 4096); // ~1.2 MB

    embed_kernel<<<SP, 256, 0, stream>>>(tokens, emb, pos, mem, x);
    // all-layer weight convert, hoisted out of the layer loop
    cvt_all_kernel<<<(4 * (4 * DD + 2 * DF)) / 1024, 256, 0, stream>>>(
        wq, wk, wv, wo, w1, w2, wAll);

    dim3 gQKV(18, 17);      // N=2304          nk = 12
    dim3 gO(6, 17, 4);      // N=768, split-K  Kc=192 -> nk = 3
    dim3 gF1(24, 17);       // N=3072          nk = 12
    dim3 gF2(6, 17, 4);     // N=768, split-K  Kc=768 -> nk = 12
    dim3 gA(NQT, NHEAD, NZ);
    dim3 gC(NQT, NHEAD);

    for (int l = 0; l < L; ++l) {
        ushort_t* wqkv = wAll + (size_t)l * PERL;
        ushort_t* wob  = wqkv + (size_t)3 * DD;
        ushort_t* w1b  = wob  + (size_t)DD;
        ushort_t* w2b  = w1b  + (size_t)DF;

        ln_kernel<ushort_t><<<SP, 256, 0, stream>>>(x, ln1_s + l * D, ln1_b + l * D, nbuf);
        gemm_mfma<<<gQKV, 512, 0, stream>>>(nbuf, wqkv, nullptr, nullptr,
                                            qkvb, D, 3 * D, 0, 0, 1);
        attn_mfma<<<gA, 256, 0, stream>>>(qkvb, Opart, mlbuf);
        attn_combine<<<gC, 256, 0, stream>>>(Opart, mlbuf, attb);
        // split-K: x already holds the residual (h); partials atomicAdd in.
        gemm_mfma<<<gO, 512, 0, stream>>>(attb, wob, nullptr, nullptr,
                                          x, D, D, 0, 0, 0);
        ln_kernel<ushort_t><<<SP, 256, 0, stream>>>(x, ln2_s + l * D, ln2_b + l * D, nbuf);
        gemm_mfma<<<gF1, 512, 0, stream>>>(nbuf, w1b, b1 + (size_t)l * FF, nullptr,
                                           ffh, D, FF, 0, 1, 1);
        gemm_mfma<<<gF2, 512, 0, stream>>>(ffh, w2b, b2 + (size_t)l * D, nullptr,
                                           x, FF, D, 0, 0, 0);
    }
    ln_kernel<float><<<NMEM, 256, 0, stream>>>(x + (size_t)(S_TOT - NMEM) * D,
                                               lnm_s, lnm_b, out);
}